// Round 9
// baseline (157.551 us; speedup 1.0000x reference)
//
#include <hip/hip_runtime.h>
#include <hip/hip_bf16.h>

#define SEQ   512
#define LPAD  64
#define RPAD  68
#define TOT   (SEQ + LPAD + RPAD)   // 644 float4 per sequence
#define C1f   14.426950408889634f    // 1/(gamma*ln2), gamma=0.1
#define K1f   0.069314718055994531f  // gamma*ln2

#if __has_builtin(__builtin_amdgcn_exp2f)
#define EXP2(x) __builtin_amdgcn_exp2f(x)
#else
#define EXP2(x) exp2f(x)
#endif

__device__ __forceinline__ float cost4(float4 X, float4 Y) {
  return fabsf(X.x - Y.x) + fabsf(X.y - Y.y) + fabsf(X.z - Y.z) + fabsf(X.w - Y.w);
}

// f64 lane shifts via DPP wave shifts: VALU, 0-fill at edges (0 == exp-domain BIG).
__device__ __forceinline__ double dshr1(double x) {  // lane t <- lane t+1; lane63 <- 0
  int lo = __builtin_amdgcn_update_dpp(0, __double2loint(x), 0x138, 0xF, 0xF, true);
  int hi = __builtin_amdgcn_update_dpp(0, __double2hiint(x), 0x138, 0xF, 0xF, true);
  return __hiloint2double(hi, lo);
}
__device__ __forceinline__ double dshl1(double x) {  // lane t <- lane t-1; lane0 <- 0
  int lo = __builtin_amdgcn_update_dpp(0, __double2loint(x), 0x130, 0xF, 0xF, true);
  int hi = __builtin_amdgcn_update_dpp(0, __double2hiint(x), 0x130, 0xF, 0xF, true);
  return __hiloint2double(hi, lo);
}
__device__ __forceinline__ double pow2i(int k) {     // 2^k exactly, |k| <= ~500
  union { unsigned long long u; double d; } v;
  v.u = ((unsigned long long)(1023 + k)) << 52;
  return v.d;
}

// ---- per-problem state (prefix p = a_ or b_), 2-parity pipeline sets A/B ----
#define DECLP(p) \
  float4 p##AX0, p##AX1, p##AYp, p##AY0, p##AYm; \
  float4 p##BX0, p##BX1, p##BYp, p##BY0, p##BYm; \
  double p##PAo0, p##PAo1, p##PAe0, p##PAe1; \
  double p##PBo0, p##PBo1, p##PBe0, p##PBe1; \
  int p##k1A, p##k2A, p##k1B, p##k2B; \
  double p##dA0, p##dA1, p##dB0, p##dB1; \
  int p##Ktot, p##bq0, p##bq1, p##k2prev;

// windows for pair m (lane-interleaved band u = 2t+s):
//   X0=x[m-62+2t], X1=x[m-61+2t]; Yp=y[m+64-2t], Y0=y[m+63-2t], Ym=y[m+62-2t]
#define LOADW(p, S, m) do { \
    p##S##X0 = p##pX[(m)];     p##S##X1 = p##pX[(m) + 1]; \
    p##S##Yp = p##pY[(m) + 1]; p##S##Y0 = p##pY[(m)];     p##S##Ym = p##pY[(m) - 1]; } while (0)

// P factors for a pair with scale bump folded into the exp2 arg.
#define COMPP(p, S, bump) do { \
    p##k1##S = (bump) >> 1; p##k2##S = (bump) - p##k1##S; \
    float _f1 = (float)p##k1##S, _f2 = (float)p##k2##S; \
    p##P##S##o0 = (double)EXP2(fmaf(cost4(p##S##X0, p##S##Y0), -C1f, _f1)); \
    p##P##S##o1 = (double)EXP2(fmaf(cost4(p##S##X1, p##S##Ym), -C1f, _f1)); \
    p##P##S##e0 = (double)EXP2(fmaf(cost4(p##S##X0, p##S##Yp), -C1f, _f2)); \
    p##P##S##e1 = (double)EXP2(fmaf(cost4(p##S##X1, p##S##Y0), -C1f, _f2)); } while (0)

// f64 recurrence for one pair (odd diag then even diag). ~8-op serial chain.
#define CHAIN(p, S) do { \
    double _s2p = pow2i(p##k2prev), _s1c = pow2i(p##k1##S); \
    double _d1p2 = dshr1(p##dB0); \
    double _nA0 = p##P##S##o0 * fma(p##dA0, _s2p, p##dB0 + p##dB1); \
    double _nA1 = p##P##S##o1 * fma(p##dA1, _s2p, p##dB1 + _d1p2); \
    double _d1m0 = dshl1(_nA1); \
    double _nB0 = p##P##S##e0 * fma(p##dB0, _s1c, _d1m0 + _nA0); \
    double _nB1 = p##P##S##e1 * fma(p##dB1, _s1c, _nA0 + _nA1); \
    p##dA0 = _nA0; p##dA1 = _nA1; p##dB0 = _nB0; p##dB1 = _nB1; } while (0)

// lag-2 reactive renorm feedback; center cell u=63 = lane31 slot1.
#define FEEDBACK(p, S) do { \
    int _hib = __builtin_amdgcn_readlane(__double2hiint(p##dB1), 31); \
    int _def = 1023 - ((_hib >> 20) & 0x7ff); \
    p##Ktot += p##bq0; \
    int _nb = _def - p##bq1; _nb = _nb < -250 ? -250 : (_nb > 250 ? 250 : _nb); \
    p##bq0 = p##bq1; p##bq1 = _nb; p##k2prev = p##k2##S; } while (0)

#define SEEDP(p, sxp, syp) do { \
    float _a0 = -C1f * cost4((sxp)[0], (syp)[0]); \
    int   _n0 = (int)floorf(_a0); \
    double _e00 = (double)EXP2(_a0 - (float)_n0); \
    p##dA0 = 0.0; p##dA1 = 0.0; \
    p##dB0 = 0.0; p##dB1 = (t == 31) ? _e00 : 0.0; \
    p##Ktot = -_n0; p##bq0 = 0; p##bq1 = 0; p##k2prev = 0; } while (0)

#define READOUT(p, q) do { \
    if (t == 31) { \
      unsigned long long _bits = __double_as_longlong(p##dB1); \
      int _ee = (int)((_bits >> 52) & 0x7ffull); \
      double _mant = __longlong_as_double((_bits & 0xFFFFFFFFFFFFFull) | (1023ull << 52)); \
      double _l2 = (double)(_ee - 1023) + (double)__log2f((float)_mant); \
      ws[q] = (float)(-(double)K1f * (_l2 - (double)p##Ktot)); \
    } } while (0)

// Blocks 0..47: TWO banded soft-DTW problems per block (q=2b, 2b+1) -> ws[q].
// Block 48: KL + transition-count losses -> ws[96..98]. Runs concurrently.
__global__ __launch_bounds__(256, 1) void sdtw_fused_kernel(
    const float* __restrict__ at,    // [32,512,4]
    const float* __restrict__ mu,    // [32,64]
    const float* __restrict__ lv,    // [32,64]
    const float* __restrict__ ptc,   // [32,1]
    const float* __restrict__ gt,    // [32,512,4]
    float* __restrict__ ws)          // [0..95]=v, [96]=klS, [97]=auxS, [98]=trS
{
  __shared__ float4 sxy[4][TOT];     // [0]=x_a, [1]=y_a, [2]=x_b, [3]=y_b
  __shared__ float s_g[32], s_ps[32], s_kl[32];

  const int blk = blockIdx.x;
  const int t   = threadIdx.x;

  if (blk < 48) {
    const int q0 = 2 * blk, q1 = 2 * blk + 1;
    auto seqs = [&](int q, const float*& xs, const float*& ys) {
      if (q < 32)      { xs = at + (size_t)q        * SEQ * 4; ys = gt + (size_t)q * SEQ * 4; }
      else if (q < 64) { xs = at + (size_t)(q - 32) * SEQ * 4; ys = xs; }
      else             { xs = gt + (size_t)(q - 64) * SEQ * 4; ys = xs; }
    };
    const float *xs0, *ys0, *xs1, *ys1;
    seqs(q0, xs0, ys0);
    seqs(q1, xs1, ys1);

    const float4 zz = make_float4(0.f, 0.f, 0.f, 0.f);
    for (int i = t; i < TOT; i += 256) {
      int j = i - LPAD;
      bool in = (j >= 0) && (j < SEQ);
      sxy[0][i] = in ? ((const float4*)xs0)[in ? j : 0] : zz;
      sxy[1][i] = in ? ((const float4*)ys0)[in ? j : 0] : zz;
      sxy[2][i] = in ? ((const float4*)xs1)[in ? j : 0] : zz;
      sxy[3][i] = in ? ((const float4*)ys1)[in ? j : 0] : zz;
    }
    __syncthreads();
    if (t >= 64) return;   // single wave runs both wavefronts; no more barriers

    const float4* a_sx = &sxy[0][LPAD];
    const float4* a_sy = &sxy[1][LPAD];
    const float4* b_sx = &sxy[2][LPAD];
    const float4* b_sy = &sxy[3][LPAD];
    const float4* a_pX = a_sx + (-62 + 2 * t);
    const float4* a_pY = a_sy + ( 63 - 2 * t);
    const float4* b_pX = b_sx + (-62 + 2 * t);
    const float4* b_pY = b_sy + ( 63 - 2 * t);

    DECLP(a_) DECLP(b_)
    SEEDP(a_, a_sx, a_sy);
    SEEDP(b_, b_sx, b_sy);

    // prologue: windows for pairs 0,1; P for pair 0 (bump 0)
    LOADW(a_, A, 0); LOADW(b_, A, 0);
    LOADW(a_, B, 1); LOADW(b_, B, 1);
    COMPP(a_, A, 0); COMPP(b_, A, 0);

    // steady: phase n = {load W(n+2), compute P(n+1), chain(n), feedback} x2 problems
    #pragma unroll 1
    for (int g = 0; g < 255; ++g) {
      // phase n = 2g (parity A)
      LOADW(a_, A, 2 * g + 2); LOADW(b_, A, 2 * g + 2);
      COMPP(a_, B, a_bq1);     COMPP(b_, B, b_bq1);
      CHAIN(a_, A);            CHAIN(b_, A);
      FEEDBACK(a_, A);         FEEDBACK(b_, A);
      // phase n = 2g+1 (parity B)
      LOADW(a_, B, 2 * g + 3); LOADW(b_, B, 2 * g + 3);
      COMPP(a_, A, a_bq1);     COMPP(b_, A, b_bq1);
      CHAIN(a_, B);            CHAIN(b_, B);
      FEEDBACK(a_, B);         FEEDBACK(b_, B);
    }
    // final pair n = 510 (parity A): chain only
    CHAIN(a_, A); CHAIN(b_, A);
    a_Ktot += a_bq0; b_Ktot += b_bq0;

    READOUT(a_, q0);
    READOUT(b_, q1);
    return;
  }

  // ---------- loss block (blk == 48), 256 threads: 8 per batch element ----------
  const int b = t >> 3, seg = t & 7;

  float s = 0.f;
  {
    const float* mb = mu + b * 64 + seg * 8;
    const float* lb = lv + b * 64 + seg * 8;
    #pragma unroll
    for (int z = 0; z < 8; ++z) {
      float m = mb[z], l = lb[z];
      s += 1.0f + l - m * m - __expf(l);
    }
  }
  s += __shfl_down(s, 4, 8);
  s += __shfl_down(s, 2, 8);
  s += __shfl_down(s, 1, 8);

  float g = 0.f, ps = 0.f;
  {
    const int n0 = seg * 64;
    const int nstart = (seg == 0) ? 1 : n0;
    const float* gb = gt + (size_t)b * SEQ * 4 + 2;
    const float* ab = at + (size_t)b * SEQ * 4 + 2;
    float pg = gb[(nstart - 1) * 4];
    float pp = 1.0f / (1.0f + __expf((0.5f - ab[(nstart - 1) * 4]) * 10.0f));
    for (int n = nstart; n < n0 + 64; ++n) {
      float cg = gb[n * 4]; g += fabsf(cg - pg); pg = cg;
      float cp = 1.0f / (1.0f + __expf((0.5f - ab[n * 4]) * 10.0f));
      ps += fabsf(cp - pp); pp = cp;
    }
  }
  g  += __shfl_down(g, 4, 8);  g  += __shfl_down(g, 2, 8);  g  += __shfl_down(g, 1, 8);
  ps += __shfl_down(ps, 4, 8); ps += __shfl_down(ps, 2, 8); ps += __shfl_down(ps, 1, 8);

  if (seg == 0) {
    s_g[b]  = g;
    s_ps[b] = ps;
    s_kl[b] = fmaxf(-0.5f * s - 0.5f, 0.0f);
  }
  __syncthreads();

  if (t < 32) {
    float gv  = s_g[t];
    float kl  = s_kl[t];
    float d   = ptc[t] - gv;  float aux = d * d;
    float e   = s_ps[t] - gv; float tr  = e * e;
    kl  += __shfl_down(kl, 16, 32); aux += __shfl_down(aux, 16, 32); tr += __shfl_down(tr, 16, 32);
    kl  += __shfl_down(kl,  8, 32); aux += __shfl_down(aux,  8, 32); tr += __shfl_down(tr,  8, 32);
    kl  += __shfl_down(kl,  4, 32); aux += __shfl_down(aux,  4, 32); tr += __shfl_down(tr,  4, 32);
    kl  += __shfl_down(kl,  2, 32); aux += __shfl_down(aux,  2, 32); tr += __shfl_down(tr,  2, 32);
    kl  += __shfl_down(kl,  1, 32); aux += __shfl_down(aux,  1, 32); tr += __shfl_down(tr,  1, 32);
    if (t == 0) { ws[96] = kl; ws[97] = aux; ws[98] = tr; }
  }
}

__global__ __launch_bounds__(64) void sdtw_combine_kernel(
    const float* __restrict__ ws, float* __restrict__ out)
{
  const int t = threadIdx.x;
  float vn = 0.f;
  if (t < 32) vn = ws[t] - 0.5f * (ws[32 + t] + ws[64 + t]);
  vn += __shfl_down(vn, 16, 32);
  vn += __shfl_down(vn,  8, 32);
  vn += __shfl_down(vn,  4, 32);
  vn += __shfl_down(vn,  2, 32);
  vn += __shfl_down(vn,  1, 32);
  if (t == 0) {
    float recon = vn * (1.0f / 1024.0f);   // mean(diag(v)) = sum/1024
    float kl    = ws[96] * (1.0f / 32.0f);
    float aux   = ws[97] * (1.0f / 32.0f);
    float tr    = ws[98] * (1.0f / 32.0f);
    out[0] = recon + kl + 0.1f * aux + 0.5f * tr;
    out[1] = recon;
    out[2] = kl;
    out[3] = aux;
    out[4] = tr;
  }
}

extern "C" void kernel_launch(void* const* d_in, const int* in_sizes, int n_in,
                              void* d_out, int out_size, void* d_ws, size_t ws_size,
                              hipStream_t stream) {
  const float* at  = (const float*)d_in[0];
  const float* mu  = (const float*)d_in[1];
  const float* lv  = (const float*)d_in[2];
  const float* ptc = (const float*)d_in[3];
  const float* gt  = (const float*)d_in[4];
  float* ws  = (float*)d_ws;
  float* out = (float*)d_out;

  sdtw_fused_kernel<<<49, 256, 0, stream>>>(at, mu, lv, ptc, gt, ws);
  sdtw_combine_kernel<<<1, 64, 0, stream>>>(ws, out);
}

// Round 10
// 86.379 us; speedup vs baseline: 1.8239x; 1.8239x over previous
//
#include <hip/hip_runtime.h>
#include <hip/hip_bf16.h>

#define SEQ   512
#define LPAD  64
#define RPAD  68
#define TOT   (SEQ + LPAD + RPAD)   // 644 float4 per sequence
#define C1f   14.426950408889634f    // 1/(gamma*ln2), gamma=0.1
#define K1f   0.069314718055994531f  // gamma*ln2

#if __has_builtin(__builtin_amdgcn_exp2f)
#define EXP2(x) __builtin_amdgcn_exp2f(x)
#else
#define EXP2(x) exp2f(x)
#endif

#define SB() __builtin_amdgcn_sched_barrier(0)

__device__ __forceinline__ float cost4(float4 X, float4 Y) {
  return fabsf(X.x - Y.x) + fabsf(X.y - Y.y) + fabsf(X.z - Y.z) + fabsf(X.w - Y.w);
}

// f64 lane shifts via DPP wave shifts: VALU, 0-fill at edges (0 == exp-domain BIG).
__device__ __forceinline__ double dshr1(double x) {  // lane t <- lane t+1; lane63 <- 0
  int lo = __builtin_amdgcn_update_dpp(0, __double2loint(x), 0x138, 0xF, 0xF, true);
  int hi = __builtin_amdgcn_update_dpp(0, __double2hiint(x), 0x138, 0xF, 0xF, true);
  return __hiloint2double(hi, lo);
}
__device__ __forceinline__ double dshl1(double x) {  // lane t <- lane t-1; lane0 <- 0
  int lo = __builtin_amdgcn_update_dpp(0, __double2loint(x), 0x130, 0xF, 0xF, true);
  int hi = __builtin_amdgcn_update_dpp(0, __double2hiint(x), 0x130, 0xF, 0xF, true);
  return __hiloint2double(hi, lo);
}
__device__ __forceinline__ double pow2i(int k) {     // 2^k exactly, |k| <= ~500
  union { unsigned long long u; double d; } v;
  v.u = ((unsigned long long)(1023 + k)) << 52;
  return v.d;
}

// ---- 3-slot rotating pipeline, lane-interleaved band u = 2t+s ----
// pair m covers diags 2m+1, 2m+2. Windows for pair m:
//   X0=x[m-62+2t], X1=x[m-61+2t]; Yp=y[m+64-2t], Y0=y[m+63-2t], Ym=y[m+62-2t]
#define DECLS(s) \
  float4 X0##s, X1##s, Yp##s, Y0##s, Ym##s; \
  double Po0##s, Po1##s, Pe0##s, Pe1##s; \
  int k1##s, k2##s;

#define LOADW(s, m) do { \
    X0##s = pX[(m)];     X1##s = pX[(m) + 1]; \
    Yp##s = pY[(m) + 1]; Y0##s = pY[(m)];     Ym##s = pY[(m) - 1]; } while (0)

// P factors for a pair with scale bump folded into the exp2 arg.
#define COMPP(s, bump) do { \
    k1##s = (bump) >> 1; k2##s = (bump) - k1##s; \
    float _f1 = (float)k1##s, _f2 = (float)k2##s; \
    Po0##s = (double)EXP2(fmaf(cost4(X0##s, Y0##s), -C1f, _f1)); \
    Po1##s = (double)EXP2(fmaf(cost4(X1##s, Ym##s), -C1f, _f1)); \
    Pe0##s = (double)EXP2(fmaf(cost4(X0##s, Yp##s), -C1f, _f2)); \
    Pe1##s = (double)EXP2(fmaf(cost4(X1##s, Y0##s), -C1f, _f2)); } while (0)

// f64 recurrence for one pair (odd diag then even diag). ~8-op serial chain.
#define CHAIN(s) do { \
    double _s2p = pow2i(k2prev), _s1c = pow2i(k1##s); \
    double _d1p2 = dshr1(dB0); \
    double _nA0 = Po0##s * fma(dA0, _s2p, dB0 + dB1); \
    double _nA1 = Po1##s * fma(dA1, _s2p, dB1 + _d1p2); \
    double _d1m0 = dshl1(_nA1); \
    double _nB0 = Pe0##s * fma(dB0, _s1c, _d1m0 + _nA0); \
    double _nB1 = Pe1##s * fma(dB1, _s1c, _nA0 + _nA1); \
    dA0 = _nA0; dA1 = _nA1; dB0 = _nB0; dB1 = _nB1; } while (0)

// lag-2 reactive renorm feedback; center cell u=63 = lane31 slot1.
#define FEEDBACK(s) do { \
    int _hib = __builtin_amdgcn_readlane(__double2hiint(dB1), 31); \
    int _def = 1023 - ((_hib >> 20) & 0x7ff); \
    Ktot += bq0; \
    int _nb = _def - bq1; _nb = _nb < -250 ? -250 : (_nb > 250 ? 250 : _nb); \
    bq0 = bq1; bq1 = _nb; k2prev = k2##s; } while (0)

// one pipeline phase n: loads for pair n+2, P for pair n+1, chain pair n
#define PHASE(sL, sC, sP, m) do { \
    SB(); \
    LOADW(sL, m); \
    COMPP(sC, bq1); \
    CHAIN(sP); \
    FEEDBACK(sP); } while (0)

// Blocks 0..95: banded soft-DTW per extended batch element -> ws[b].
// Block 96: KL + transition-count losses -> ws[96..98]. Runs concurrently.
__global__ __launch_bounds__(256, 1) void sdtw_fused_kernel(
    const float* __restrict__ at,    // [32,512,4]
    const float* __restrict__ mu,    // [32,64]
    const float* __restrict__ lv,    // [32,64]
    const float* __restrict__ ptc,   // [32,1]
    const float* __restrict__ gt,    // [32,512,4]
    float* __restrict__ ws)          // [0..95]=v, [96]=klS, [97]=auxS, [98]=trS
{
  __shared__ float4 sx[TOT];
  __shared__ float4 sy[TOT];
  __shared__ float s_g[32], s_ps[32], s_kl[32];

  const int blk = blockIdx.x;
  const int t   = threadIdx.x;

  if (blk < 96) {
    const float* xs;
    const float* ys;
    if (blk < 32)      { xs = at + (size_t)blk        * SEQ * 4; ys = gt + (size_t)blk * SEQ * 4; }
    else if (blk < 64) { xs = at + (size_t)(blk - 32) * SEQ * 4; ys = xs; }
    else               { xs = gt + (size_t)(blk - 64) * SEQ * 4; ys = xs; }

    for (int i = t; i < LPAD; i += 256) {
      sx[i] = make_float4(0.f, 0.f, 0.f, 0.f);
      sy[i] = make_float4(0.f, 0.f, 0.f, 0.f);
    }
    for (int i = LPAD + SEQ + t; i < TOT; i += 256) {
      sx[i] = make_float4(0.f, 0.f, 0.f, 0.f);
      sy[i] = make_float4(0.f, 0.f, 0.f, 0.f);
    }
    for (int i = t; i < SEQ; i += 256) {
      sx[LPAD + i] = ((const float4*)xs)[i];
      sy[LPAD + i] = ((const float4*)ys)[i];
    }
    __syncthreads();
    if (t >= 64) return;   // single wave runs the wavefront; no more barriers

    const float4* sxp = sx + LPAD;
    const float4* syp = sy + LPAD;
    const float4* pX = sxp + (-62 + 2 * t);
    const float4* pY = syp + ( 63 - 2 * t);

    // state init: diag -1 (dA) = 0; diag 0 (dB): (0,0) at u=63 (lane31 slot1).
    float a0 = -C1f * cost4(sxp[0], syp[0]);
    int   n0 = (int)floorf(a0);
    double e00 = (double)EXP2(a0 - (float)n0);
    double dA0 = 0.0, dA1 = 0.0;
    double dB0 = 0.0, dB1 = (t == 31) ? e00 : 0.0;
    int Ktot = -n0;
    int bq0 = 0, bq1 = 0, k2prev = 0;

    DECLS(0) DECLS(1) DECLS(2)

    // prologue: windows for pairs 0,1; P for pair 0 (bump 0)
    LOADW(0, 0);
    LOADW(1, 1);
    COMPP(0, 0);

    // steady: 510 phases (n = 0..509), slot = index mod 3, pinned by SB fences
    #pragma unroll 1
    for (int g = 0; g < 170; ++g) {
      const int n = 3 * g;
      PHASE(2, 1, 0, n + 2);   // n
      PHASE(0, 2, 1, n + 3);   // n+1
      PHASE(1, 0, 2, n + 4);   // n+2
    }
    SB();
    CHAIN(0);                  // pair 510
    Ktot += bq0;

    if (t == 31) {
      // v = -gamma*ln(E_true) = -K1f*(log2(stored) - Ktot)
      unsigned long long bits = __double_as_longlong(dB1);
      int ee = (int)((bits >> 52) & 0x7ffull);
      double mant = __longlong_as_double((bits & 0xFFFFFFFFFFFFFull) | (1023ull << 52));
      double l2 = (double)(ee - 1023) + (double)__log2f((float)mant);
      ws[blk] = (float)(-(double)K1f * (l2 - (double)Ktot));
    }
    return;
  }

  // ---------- loss block (blk == 96), 256 threads: 8 per batch element ----------
  const int b = t >> 3, seg = t & 7;

  float s = 0.f;
  {
    const float* mb = mu + b * 64 + seg * 8;
    const float* lb = lv + b * 64 + seg * 8;
    #pragma unroll
    for (int z = 0; z < 8; ++z) {
      float m = mb[z], l = lb[z];
      s += 1.0f + l - m * m - __expf(l);
    }
  }
  s += __shfl_down(s, 4, 8);
  s += __shfl_down(s, 2, 8);
  s += __shfl_down(s, 1, 8);

  float g = 0.f, ps = 0.f;
  {
    const int n0 = seg * 64;
    const int nstart = (seg == 0) ? 1 : n0;
    const float* gb = gt + (size_t)b * SEQ * 4 + 2;
    const float* ab = at + (size_t)b * SEQ * 4 + 2;
    float pg = gb[(nstart - 1) * 4];
    float pp = 1.0f / (1.0f + __expf((0.5f - ab[(nstart - 1) * 4]) * 10.0f));
    for (int n = nstart; n < n0 + 64; ++n) {
      float cg = gb[n * 4]; g += fabsf(cg - pg); pg = cg;
      float cp = 1.0f / (1.0f + __expf((0.5f - ab[n * 4]) * 10.0f));
      ps += fabsf(cp - pp); pp = cp;
    }
  }
  g  += __shfl_down(g, 4, 8);  g  += __shfl_down(g, 2, 8);  g  += __shfl_down(g, 1, 8);
  ps += __shfl_down(ps, 4, 8); ps += __shfl_down(ps, 2, 8); ps += __shfl_down(ps, 1, 8);

  if (seg == 0) {
    s_g[b]  = g;
    s_ps[b] = ps;
    s_kl[b] = fmaxf(-0.5f * s - 0.5f, 0.0f);
  }
  __syncthreads();

  if (t < 32) {
    float gv  = s_g[t];
    float kl  = s_kl[t];
    float d   = ptc[t] - gv;  float aux = d * d;
    float e   = s_ps[t] - gv; float tr  = e * e;
    kl  += __shfl_down(kl, 16, 32); aux += __shfl_down(aux, 16, 32); tr += __shfl_down(tr, 16, 32);
    kl  += __shfl_down(kl,  8, 32); aux += __shfl_down(aux,  8, 32); tr += __shfl_down(tr,  8, 32);
    kl  += __shfl_down(kl,  4, 32); aux += __shfl_down(aux,  4, 32); tr += __shfl_down(tr,  4, 32);
    kl  += __shfl_down(kl,  2, 32); aux += __shfl_down(aux,  2, 32); tr += __shfl_down(tr,  2, 32);
    kl  += __shfl_down(kl,  1, 32); aux += __shfl_down(aux,  1, 32); tr += __shfl_down(tr,  1, 32);
    if (t == 0) { ws[96] = kl; ws[97] = aux; ws[98] = tr; }
  }
}

__global__ __launch_bounds__(64) void sdtw_combine_kernel(
    const float* __restrict__ ws, float* __restrict__ out)
{
  const int t = threadIdx.x;
  float vn = 0.f;
  if (t < 32) vn = ws[t] - 0.5f * (ws[32 + t] + ws[64 + t]);
  vn += __shfl_down(vn, 16, 32);
  vn += __shfl_down(vn,  8, 32);
  vn += __shfl_down(vn,  4, 32);
  vn += __shfl_down(vn,  2, 32);
  vn += __shfl_down(vn,  1, 32);
  if (t == 0) {
    float recon = vn * (1.0f / 1024.0f);   // mean(diag(v)) = sum/1024
    float kl    = ws[96] * (1.0f / 32.0f);
    float aux   = ws[97] * (1.0f / 32.0f);
    float tr    = ws[98] * (1.0f / 32.0f);
    out[0] = recon + kl + 0.1f * aux + 0.5f * tr;
    out[1] = recon;
    out[2] = kl;
    out[3] = aux;
    out[4] = tr;
  }
}

extern "C" void kernel_launch(void* const* d_in, const int* in_sizes, int n_in,
                              void* d_out, int out_size, void* d_ws, size_t ws_size,
                              hipStream_t stream) {
  const float* at  = (const float*)d_in[0];
  const float* mu  = (const float*)d_in[1];
  const float* lv  = (const float*)d_in[2];
  const float* ptc = (const float*)d_in[3];
  const float* gt  = (const float*)d_in[4];
  float* ws  = (float*)d_ws;
  float* out = (float*)d_out;

  sdtw_fused_kernel<<<97, 256, 0, stream>>>(at, mu, lv, ptc, gt, ws);
  sdtw_combine_kernel<<<1, 64, 0, stream>>>(ws, out);
}

// Round 11
// 65.077 us; speedup vs baseline: 2.4210x; 1.3273x over previous
//
#include <hip/hip_runtime.h>
#include <hip/hip_bf16.h>

#define SEQ   512
#define LPAD  64
#define RPAD  68
#define TOT   (SEQ + LPAD + RPAD)   // 644 float4 per sequence
#define C1f   14.426950408889634f    // 1/(gamma*ln2), gamma=0.1
#define K1f   0.069314718055994531f  // gamma*ln2

#if __has_builtin(__builtin_amdgcn_exp2f)
#define EXP2(x) __builtin_amdgcn_exp2f(x)
#else
#define EXP2(x) exp2f(x)
#endif

#define SB() __builtin_amdgcn_sched_barrier(0)

__device__ __forceinline__ float cost4(float4 X, float4 Y) {
  return fabsf(X.x - Y.x) + fabsf(X.y - Y.y) + fabsf(X.z - Y.z) + fabsf(X.w - Y.w);
}

// f64 lane shifts via DPP wave shifts: VALU, 0-fill at edges (0 == exp-domain BIG).
__device__ __forceinline__ double dshr1(double x) {  // lane t <- lane t+1; lane63 <- 0
  int lo = __builtin_amdgcn_update_dpp(0, __double2loint(x), 0x138, 0xF, 0xF, true);
  int hi = __builtin_amdgcn_update_dpp(0, __double2hiint(x), 0x138, 0xF, 0xF, true);
  return __hiloint2double(hi, lo);
}
__device__ __forceinline__ double dshl1(double x) {  // lane t <- lane t-1; lane0 <- 0
  int lo = __builtin_amdgcn_update_dpp(0, __double2loint(x), 0x130, 0xF, 0xF, true);
  int hi = __builtin_amdgcn_update_dpp(0, __double2hiint(x), 0x130, 0xF, 0xF, true);
  return __hiloint2double(hi, lo);
}
__device__ __forceinline__ double pow2i(int k) {     // 2^k exactly, |k| <= ~500
  union { unsigned long long u; double d; } v;
  v.u = ((unsigned long long)(1023 + k)) << 52;
  return v.d;
}

// ---- 1 cell/lane, band u = t in [0,63] ----
// pair n covers diags p=2n+1 (odd) and p=2n+2 (even).
//   odd  cell: i = n+t-31, j = n-t+32   (d = 2t-63)
//   even cell: i = n+t-30, j = n-t+32   (d = 2t-62)
// neighbors (verified adjacency):
//   odd : diag = dA(same lane), left = dB(same lane), up = dshl1(dB)
//   even: diag = dB(same lane), up = nA(same lane),  left = dshr1(nA)
// windows: X0 = x[n+t-31], X1 = x[n+t-30], Y0 = y[n-t+32]  (Y shared by both diags)
#define DECLS(s) \
  float4 X0##s, X1##s, Y0##s; \
  double Po##s, Pe##s; \
  int k1##s, k2##s;

#define LOADW(s, m) do { \
    X0##s = pX[(m)]; X1##s = pX[(m) + 1]; Y0##s = pY[(m)]; } while (0)

// P factors for a pair with scale bump folded into the exp2 arg.
#define COMPP(s, bump) do { \
    k1##s = (bump) >> 1; k2##s = (bump) - k1##s; \
    float _f1 = (float)k1##s, _f2 = (float)k2##s; \
    Po##s = (double)EXP2(fmaf(cost4(X0##s, Y0##s), -C1f, _f1)); \
    Pe##s = (double)EXP2(fmaf(cost4(X1##s, Y0##s), -C1f, _f2)); } while (0)

// f64 recurrence for one pair (odd diag then even diag).
#define CHAIN(s) do { \
    double _s2p = pow2i(k2prev), _s1c = pow2i(k1##s); \
    double _up = dshl1(dB); \
    double _nA = Po##s * fma(dA, _s2p, dB + _up); \
    double _lf = dshr1(_nA); \
    double _nB = Pe##s * fma(dB, _s1c, _nA + _lf); \
    dA = _nA; dB = _nB; } while (0)

// lag-2 reactive renorm feedback; center cell = lane31 (even diag (n+1,n+1), always valid).
#define FEEDBACK(s) do { \
    int _hib = __builtin_amdgcn_readlane(__double2hiint(dB), 31); \
    int _def = 1023 - ((_hib >> 20) & 0x7ff); \
    Ktot += bq0; \
    int _nb = _def - bq1; _nb = _nb < -250 ? -250 : (_nb > 250 ? 250 : _nb); \
    bq0 = bq1; bq1 = _nb; k2prev = k2##s; } while (0)

// one pipeline phase n: loads for pair n+2, P for pair n+1, chain pair n
#define PHASE(sL, sC, sP, m) do { \
    SB(); \
    LOADW(sL, m); \
    COMPP(sC, bq1); \
    CHAIN(sP); \
    FEEDBACK(sP); } while (0)

// Blocks 0..95: banded soft-DTW per extended batch element -> ws[b].
// Block 96: KL + transition-count losses -> ws[96..98]. Runs concurrently.
__global__ __launch_bounds__(256, 1) void sdtw_fused_kernel(
    const float* __restrict__ at,    // [32,512,4]
    const float* __restrict__ mu,    // [32,64]
    const float* __restrict__ lv,    // [32,64]
    const float* __restrict__ ptc,   // [32,1]
    const float* __restrict__ gt,    // [32,512,4]
    float* __restrict__ ws)          // [0..95]=v, [96]=klS, [97]=auxS, [98]=trS
{
  __shared__ float4 sx[TOT];
  __shared__ float4 sy[TOT];
  __shared__ float s_g[32], s_ps[32], s_kl[32];

  const int blk = blockIdx.x;
  const int t   = threadIdx.x;

  if (blk < 96) {
    const float* xs;
    const float* ys;
    if (blk < 32)      { xs = at + (size_t)blk        * SEQ * 4; ys = gt + (size_t)blk * SEQ * 4; }
    else if (blk < 64) { xs = at + (size_t)(blk - 32) * SEQ * 4; ys = xs; }
    else               { xs = gt + (size_t)(blk - 64) * SEQ * 4; ys = xs; }

    for (int i = t; i < LPAD; i += 256) {
      sx[i] = make_float4(0.f, 0.f, 0.f, 0.f);
      sy[i] = make_float4(0.f, 0.f, 0.f, 0.f);
    }
    for (int i = LPAD + SEQ + t; i < TOT; i += 256) {
      sx[i] = make_float4(0.f, 0.f, 0.f, 0.f);
      sy[i] = make_float4(0.f, 0.f, 0.f, 0.f);
    }
    for (int i = t; i < SEQ; i += 256) {
      sx[LPAD + i] = ((const float4*)xs)[i];
      sy[LPAD + i] = ((const float4*)ys)[i];
    }
    __syncthreads();
    if (t >= 64) return;   // single wave runs the wavefront; no more barriers

    const float4* sxp = sx + LPAD;
    const float4* syp = sy + LPAD;
    const float4* pX = sxp + (t - 31);   // pX[n] = x[n+t-31]
    const float4* pY = syp + (32 - t);   // pY[n] = y[n-t+32]

    // state init: diag -1/0 analog: dA (diag 2n) = 0 except seed at lane31 via dB?
    // Seed: diag 0 holds (0,0) at even-formula n=-1, u=31 -> dB = e00 at lane31.
    float a0 = -C1f * cost4(sxp[0], syp[0]);
    int   n0 = (int)floorf(a0);
    double e00 = (double)EXP2(a0 - (float)n0);
    double dA = 0.0;                       // diag 2n-1 (odd of prev pair)
    double dB = (t == 31) ? e00 : 0.0;     // diag 2n   (even of prev pair)
    int Ktot = -n0;
    int bq0 = 0, bq1 = 0, k2prev = 0;

    DECLS(0) DECLS(1) DECLS(2)

    // prologue: windows for pairs 0,1; P for pair 0 (bump 0)
    LOADW(0, 0);
    LOADW(1, 1);
    COMPP(0, 0);

    // steady: 510 phases (pairs 0..509), slot = phase mod 3, pinned by SB fences
    #pragma unroll 1
    for (int g = 0; g < 170; ++g) {
      const int n = 3 * g;
      PHASE(2, 1, 0, n + 2);   // phase n
      PHASE(0, 2, 1, n + 3);   // phase n+1
      PHASE(1, 0, 2, n + 4);   // phase n+2
    }
    SB();
    CHAIN(0);                  // pair 510
    Ktot += bq0;

    if (t == 31) {
      // final cell (511,511) = even diag of pair 510, lane31
      // v = -gamma*ln(E_true) = -K1f*(log2(stored) - Ktot)
      unsigned long long bits = __double_as_longlong(dB);
      int ee = (int)((bits >> 52) & 0x7ffull);
      double mant = __longlong_as_double((bits & 0xFFFFFFFFFFFFFull) | (1023ull << 52));
      double l2 = (double)(ee - 1023) + (double)__log2f((float)mant);
      ws[blk] = (float)(-(double)K1f * (l2 - (double)Ktot));
    }
    return;
  }

  // ---------- loss block (blk == 96), 256 threads: 8 per batch element ----------
  const int b = t >> 3, seg = t & 7;

  float s = 0.f;
  {
    const float* mb = mu + b * 64 + seg * 8;
    const float* lb = lv + b * 64 + seg * 8;
    #pragma unroll
    for (int z = 0; z < 8; ++z) {
      float m = mb[z], l = lb[z];
      s += 1.0f + l - m * m - __expf(l);
    }
  }
  s += __shfl_down(s, 4, 8);
  s += __shfl_down(s, 2, 8);
  s += __shfl_down(s, 1, 8);

  float g = 0.f, ps = 0.f;
  {
    const int n0 = seg * 64;
    const int nstart = (seg == 0) ? 1 : n0;
    const float* gb = gt + (size_t)b * SEQ * 4 + 2;
    const float* ab = at + (size_t)b * SEQ * 4 + 2;
    float pg = gb[(nstart - 1) * 4];
    float pp = 1.0f / (1.0f + __expf((0.5f - ab[(nstart - 1) * 4]) * 10.0f));
    for (int n = nstart; n < n0 + 64; ++n) {
      float cg = gb[n * 4]; g += fabsf(cg - pg); pg = cg;
      float cp = 1.0f / (1.0f + __expf((0.5f - ab[n * 4]) * 10.0f));
      ps += fabsf(cp - pp); pp = cp;
    }
  }
  g  += __shfl_down(g, 4, 8);  g  += __shfl_down(g, 2, 8);  g  += __shfl_down(g, 1, 8);
  ps += __shfl_down(ps, 4, 8); ps += __shfl_down(ps, 2, 8); ps += __shfl_down(ps, 1, 8);

  if (seg == 0) {
    s_g[b]  = g;
    s_ps[b] = ps;
    s_kl[b] = fmaxf(-0.5f * s - 0.5f, 0.0f);
  }
  __syncthreads();

  if (t < 32) {
    float gv  = s_g[t];
    float kl  = s_kl[t];
    float d   = ptc[t] - gv;  float aux = d * d;
    float e   = s_ps[t] - gv; float tr  = e * e;
    kl  += __shfl_down(kl, 16, 32); aux += __shfl_down(aux, 16, 32); tr += __shfl_down(tr, 16, 32);
    kl  += __shfl_down(kl,  8, 32); aux += __shfl_down(aux,  8, 32); tr += __shfl_down(tr,  8, 32);
    kl  += __shfl_down(kl,  4, 32); aux += __shfl_down(aux,  4, 32); tr += __shfl_down(tr,  4, 32);
    kl  += __shfl_down(kl,  2, 32); aux += __shfl_down(aux,  2, 32); tr += __shfl_down(tr,  2, 32);
    kl  += __shfl_down(kl,  1, 32); aux += __shfl_down(aux,  1, 32); tr += __shfl_down(tr,  1, 32);
    if (t == 0) { ws[96] = kl; ws[97] = aux; ws[98] = tr; }
  }
}

__global__ __launch_bounds__(64) void sdtw_combine_kernel(
    const float* __restrict__ ws, float* __restrict__ out)
{
  const int t = threadIdx.x;
  float vn = 0.f;
  if (t < 32) vn = ws[t] - 0.5f * (ws[32 + t] + ws[64 + t]);
  vn += __shfl_down(vn, 16, 32);
  vn += __shfl_down(vn,  8, 32);
  vn += __shfl_down(vn,  4, 32);
  vn += __shfl_down(vn,  2, 32);
  vn += __shfl_down(vn,  1, 32);
  if (t == 0) {
    float recon = vn * (1.0f / 1024.0f);   // mean(diag(v)) = sum/1024
    float kl    = ws[96] * (1.0f / 32.0f);
    float aux   = ws[97] * (1.0f / 32.0f);
    float tr    = ws[98] * (1.0f / 32.0f);
    out[0] = recon + kl + 0.1f * aux + 0.5f * tr;
    out[1] = recon;
    out[2] = kl;
    out[3] = aux;
    out[4] = tr;
  }
}

extern "C" void kernel_launch(void* const* d_in, const int* in_sizes, int n_in,
                              void* d_out, int out_size, void* d_ws, size_t ws_size,
                              hipStream_t stream) {
  const float* at  = (const float*)d_in[0];
  const float* mu  = (const float*)d_in[1];
  const float* lv  = (const float*)d_in[2];
  const float* ptc = (const float*)d_in[3];
  const float* gt  = (const float*)d_in[4];
  float* ws  = (float*)d_ws;
  float* out = (float*)d_out;

  sdtw_fused_kernel<<<97, 256, 0, stream>>>(at, mu, lv, ptc, gt, ws);
  sdtw_combine_kernel<<<1, 64, 0, stream>>>(ws, out);
}